// Round 1
// baseline (210.844 us; speedup 1.0000x reference)
//
#include <hip/hip_runtime.h>

// Problem constants (from reference: shape (32,1,512,512) fp32)
#define BATCH 32
#define H 512
#define W 512
#define N_TOT (BATCH * H * W)   // 8388608

// Tile config: 256 threads, 64-wide x 16-tall output tile, halo of 1.
#define TW 64
#define TH 16
#define SR (TH + 2)   // 18 tile rows
#define SC (TW + 2)   // 66 tile cols
#define SELEMS (SR * SC)

// Fused kernel: computes sum over pixels of
//   |AB - F|  +  |sobel(F) - max(sobel(A), sobel(B))|
// (the reference's cs_loss is multiplied by 0.0 and is finite, so it is
//  exactly dropped). Each block atomically adds its pre-scaled partial sum.
__global__ __launch_bounds__(256)
void fusion_loss_kernel(const float* __restrict__ A,
                        const float* __restrict__ B,
                        const float* __restrict__ F,
                        const int* __restrict__ scheme_arr,
                        float* __restrict__ out)
{
    __shared__ float sA[SELEMS];
    __shared__ float sB[SELEMS];
    __shared__ float sF[SELEMS];
    __shared__ float red[4];

    const int t  = threadIdx.x;
    const int b  = blockIdx.z;
    const int x0 = blockIdx.x * TW;
    const int y0 = blockIdx.y * TH;
    const size_t base = (size_t)b * (H * W);

    // ---- stage tile (with zero-padded halo) into LDS, coalesced rows ----
    for (int i = t; i < SELEMS; i += 256) {
        int r  = i / SC;
        int c  = i - r * SC;
        int yy = y0 - 1 + r;
        int xx = x0 - 1 + c;
        float va = 0.f, vb = 0.f, vf = 0.f;
        if (yy >= 0 && yy < H && xx >= 0 && xx < W) {
            size_t off = base + (size_t)yy * W + xx;
            va = A[off];
            vb = B[off];
            vf = F[off];
        }
        sA[i] = va;
        sB[i] = vb;
        sF[i] = vf;
    }
    __syncthreads();

    const int tx  = t & 63;   // column within tile (wave-contiguous -> no LDS conflicts)
    const int ty  = t >> 6;   // wave id 0..3
    const int ly0 = ty * 4;   // this thread's first output row in the tile
    const int scheme = scheme_arr[b];

    // Separable Sobel row sums over the 6 tile rows this thread needs.
    // h1 = row conv [-1,0,1], h2 = row conv [1,2,1]; centers kept for l_loss.
    float h1A[6], h2A[6], h1B[6], h2B[6], h1F[6], h2F[6];
    float cA[6], cB[6], cF[6];
#pragma unroll
    for (int k = 0; k < 6; ++k) {
        int idx = (ly0 + k) * SC + tx;
        float a0 = sA[idx], a1 = sA[idx + 1], a2 = sA[idx + 2];
        float b0 = sB[idx], b1 = sB[idx + 1], b2 = sB[idx + 2];
        float f0 = sF[idx], f1 = sF[idx + 1], f2 = sF[idx + 2];
        h1A[k] = a2 - a0;  h2A[k] = a0 + 2.f * a1 + a2;  cA[k] = a1;
        h1B[k] = b2 - b0;  h2B[k] = b0 + 2.f * b1 + b2;  cB[k] = b1;
        h1F[k] = f2 - f0;  h2F[k] = f0 + 2.f * f1 + f2;  cF[k] = f1;
    }

    float acc = 0.f;
#pragma unroll
    for (int k = 0; k < 4; ++k) {
        // vertical combine: gx = [1,2,1]^T * h1, gy = h2[top] - h2[bottom]
        float gxA = h1A[k] + 2.f * h1A[k + 1] + h1A[k + 2];
        float gyA = h2A[k] - h2A[k + 2];
        float sobA = fabsf(gxA) + fabsf(gyA);

        float gxB = h1B[k] + 2.f * h1B[k + 1] + h1B[k + 2];
        float gyB = h2B[k] - h2B[k + 2];
        float sobB = fabsf(gxB) + fabsf(gyB);

        float gxF = h1F[k] + 2.f * h1F[k + 1] + h1F[k + 2];
        float gyF = h2F[k] - h2F[k + 2];
        float sobF = fabsf(gxF) + fabsf(gyF);

        acc += fabsf(sobF - fmaxf(sobA, sobB));

        // l_loss term at the center pixel (tile row ly0+k+1, col tx+1)
        float av = cA[k + 1], bv = cB[k + 1], fv = cF[k + 1];
        float ab = (scheme == 0) ? 0.5f * (av + bv)
                 : (scheme == 1) ? fmaxf(av, bv)
                 : 0.f;
        acc += fabsf(ab - fv);
    }

    // ---- reduction: wave (64-lane) shuffle, then cross-wave via LDS ----
#pragma unroll
    for (int off = 32; off > 0; off >>= 1)
        acc += __shfl_down(acc, off, 64);
    if (tx == 0) red[ty] = acc;
    __syncthreads();
    if (t == 0) {
        float s = red[0] + red[1] + red[2] + red[3];
        atomicAdd(out, s * (1.0f / (float)N_TOT));
    }
}

extern "C" void kernel_launch(void* const* d_in, const int* in_sizes, int n_in,
                              void* d_out, int out_size, void* d_ws, size_t ws_size,
                              hipStream_t stream)
{
    const float* A = (const float*)d_in[0];
    const float* B = (const float*)d_in[1];
    const float* F = (const float*)d_in[2];
    const int* scheme = (const int*)d_in[3];
    float* out = (float*)d_out;

    // d_out is poisoned before every launch; zero it for the atomics.
    hipMemsetAsync(out, 0, sizeof(float), stream);

    dim3 grid(W / TW, H / TH, BATCH);   // 8 x 32 x 32 = 8192 blocks
    dim3 block(256);
    fusion_loss_kernel<<<grid, block, 0, stream>>>(A, B, F, scheme, out);
}

// Round 2
// 163.157 us; speedup vs baseline: 1.2923x; 1.2923x over previous
//
#include <hip/hip_runtime.h>

// Problem constants (from reference: shape (32,1,512,512) fp32)
#define BATCH 32
#define H 512
#define W 512
#define N_TOT (BATCH * H * W)   // 8388608

// Tile: 128 wide x 16 tall outputs, halo 1 row vertical, 4 floats horizontal
// (padded to float4 alignment). LDS = 3 * 18 * 136 * 4B = 29.4 KB.
#define TW 128
#define TH 16
#define SR (TH + 2)          // 18 LDS rows
#define SC4 (TW / 4 + 2)     // 34 float4 per LDS row
#define SCF (SC4 * 4)        // 136 floats per LDS row
#define IMG_F4 (SR * SC4)    // 612 float4 per image tile

__global__ __launch_bounds__(256)
void fusion_loss_kernel(const float* __restrict__ A,
                        const float* __restrict__ B,
                        const float* __restrict__ F,
                        const int* __restrict__ scheme_arr,
                        float* __restrict__ out)
{
    __shared__ float sA[SR * SCF];
    __shared__ float sB[SR * SCF];
    __shared__ float sF[SR * SCF];
    __shared__ float red[4];

    const int t  = threadIdx.x;
    const int b  = blockIdx.z;
    const int x0 = blockIdx.x * TW;
    const int y0 = blockIdx.y * TH;
    const size_t base = (size_t)b * (size_t)(H * W);
    const int scheme = scheme_arr[b];

    float acc = 0.f;

    // ---- stage tile into LDS with float4 loads (9 independent loads/thread,
    //      fully unrolled -> high MLP); fold l_loss in on the register values ----
#pragma unroll
    for (int j = 0; j < 3; ++j) {
        const int idx = t + j * 256;
        const bool active = (idx < IMG_F4);
        const int r  = idx / SC4;          // const-div -> mul/shift
        const int c4 = idx - r * SC4;
        const int yy = y0 - 1 + r;
        const int xx = x0 - 4 + c4 * 4;    // float4-aligned global col
        float4 va = make_float4(0.f, 0.f, 0.f, 0.f), vb = va, vf = va;
        if (active && (unsigned)yy < (unsigned)H && (unsigned)xx < (unsigned)W) {
            const size_t off = base + (size_t)yy * W + xx;
            va = *reinterpret_cast<const float4*>(A + off);
            vb = *reinterpret_cast<const float4*>(B + off);
            vf = *reinterpret_cast<const float4*>(F + off);
        }
        if (active) {
            const int so = r * SCF + c4 * 4;
            *reinterpret_cast<float4*>(&sA[so]) = va;
            *reinterpret_cast<float4*>(&sB[so]) = vb;
            *reinterpret_cast<float4*>(&sF[so]) = vf;
            // l_loss: count each interior (output-tile) pixel exactly once
            if (r >= 1 && r <= TH && c4 >= 1 && c4 <= TW / 4) {
                const float ax[4] = {va.x, va.y, va.z, va.w};
                const float bx[4] = {vb.x, vb.y, vb.z, vb.w};
                const float fx[4] = {vf.x, vf.y, vf.z, vf.w};
#pragma unroll
                for (int c = 0; c < 4; ++c) {
                    const float ab = (scheme == 0) ? 0.5f * (ax[c] + bx[c])
                                   : (scheme == 1) ? fmaxf(ax[c], bx[c])
                                   : 0.f;
                    acc += fabsf(ab - fx[c]);
                }
            }
        }
    }
    __syncthreads();

    // ---- grad_loss: each thread owns 4 cols x 2 rows; separable Sobel.
    //      All LDS reads are aligned ds_read_b128 (stride 16B across lanes,
    //      conflict-free); no scalar stride-4 reads. ----
    const int ctx = t & 31;            // 32 col-groups of 4
    const int cty = t >> 5;            // 8 row-groups of 2
    const int cbase = 4 * ctx + 4;     // LDS float col of first output col
    const int lr0 = 2 * cty;           // LDS rows lr0..lr0+3 needed

    float sob[3][2][4];
    const float* imgs[3] = {sA, sB, sF};
#pragma unroll
    for (int im = 0; im < 3; ++im) {
        const float* s = imgs[im];
        float h1[4][4], h2[4][4];      // row convs: h1 = [-1,0,1], h2 = [1,2,1]
#pragma unroll
        for (int rr = 0; rr < 4; ++rr) {
            const float* row = s + (lr0 + rr) * SCF + cbase;
            const float4 vm = *reinterpret_cast<const float4*>(row - 4);
            const float4 v  = *reinterpret_cast<const float4*>(row);
            const float4 vp = *reinterpret_cast<const float4*>(row + 4);
            const float l = vm.w, rgt = vp.x;
            h1[rr][0] = v.y - l;    h2[rr][0] = l   + 2.f * v.x + v.y;
            h1[rr][1] = v.z - v.x;  h2[rr][1] = v.x + 2.f * v.y + v.z;
            h1[rr][2] = v.w - v.y;  h2[rr][2] = v.y + 2.f * v.z + v.w;
            h1[rr][3] = rgt - v.z;  h2[rr][3] = v.z + 2.f * v.w + rgt;
        }
#pragma unroll
        for (int o = 0; o < 2; ++o)
#pragma unroll
            for (int c = 0; c < 4; ++c) {
                const float gx = h1[o][c] + 2.f * h1[o + 1][c] + h1[o + 2][c];
                const float gy = h2[o][c] - h2[o + 2][c];
                sob[im][o][c] = fabsf(gx) + fabsf(gy);
            }
    }
#pragma unroll
    for (int o = 0; o < 2; ++o)
#pragma unroll
        for (int c = 0; c < 4; ++c)
            acc += fabsf(sob[2][o][c] - fmaxf(sob[0][o][c], sob[1][o][c]));

    // ---- reduction: 64-lane shuffle, then cross-wave via LDS, one atomic ----
#pragma unroll
    for (int off = 32; off > 0; off >>= 1)
        acc += __shfl_down(acc, off, 64);
    if ((t & 63) == 0) red[t >> 6] = acc;
    __syncthreads();
    if (t == 0)
        atomicAdd(out, (red[0] + red[1] + red[2] + red[3]) * (1.0f / (float)N_TOT));
}

extern "C" void kernel_launch(void* const* d_in, const int* in_sizes, int n_in,
                              void* d_out, int out_size, void* d_ws, size_t ws_size,
                              hipStream_t stream)
{
    const float* A = (const float*)d_in[0];
    const float* B = (const float*)d_in[1];
    const float* F = (const float*)d_in[2];
    const int* scheme = (const int*)d_in[3];
    float* out = (float*)d_out;

    // d_out is poisoned before every launch; zero it for the atomics.
    hipMemsetAsync(out, 0, sizeof(float), stream);

    dim3 grid(W / TW, H / TH, BATCH);   // 4 x 32 x 32 = 4096 blocks
    dim3 block(256);
    fusion_loss_kernel<<<grid, block, 0, stream>>>(A, B, F, scheme, out);
}